// Round 4
// baseline (1659.234 us; speedup 1.0000x reference)
//
#include <hip/hip_runtime.h>
#include <stdint.h>

typedef unsigned int u32;
typedef unsigned long long u64;

constexpr int NP = 16384;   // points per batch
// ---- fixed float-region offsets (in floats) ----
constexpr int W0T = 0;        // [8][64]   (k<7 valid, transposed)
constexpr int W1T = 512;      // [64][64]
constexpr int W2T = 4608;     // [64][64]
constexpr int W3T = 8704;     // [64][128]
constexpr int B0F = 16896, B1F = 16960, B2F = 17024, B3F = 17088, B4F = 17216;
constexpr int GFO = 18240;    // gf  [16][1024]
constexpr int GCFO = 34624;   // gcf [4][1024]
constexpr int OF1O = 38720;   // of1 [16][512]
constexpr int GR1O = 46912;   // gr1 [512]
constexpr int FIXED_FLOATS = 47424;
constexpr u32 FIXED_BYTES = FIXED_FLOATS * 4;   // 189696, 8B-aligned

struct __align__(16) f4 { float x, y, z, w; };

__device__ __forceinline__ void fma4(f4& c, float s, const f4& a){
  c.x = fmaf(s, a.x, c.x); c.y = fmaf(s, a.y, c.y);
  c.z = fmaf(s, a.z, c.z); c.w = fmaf(s, a.w, c.w);
}

// ---------------- prep: transpose weights to [k][o], zero reduce scratch ----------------
__global__ __launch_bounds__(256) void k_prep(
    const float* __restrict__ wl0, const float* __restrict__ wl1, const float* __restrict__ wl2,
    const float* __restrict__ wl3, const float* __restrict__ wl4,
    const float* __restrict__ bl0, const float* __restrict__ bl1, const float* __restrict__ bl2,
    const float* __restrict__ bl3, const float* __restrict__ bl4,
    float* __restrict__ wsf, u32 pmax_off, u32 gmax_off, u32 w5_off, int P, int G)
{
  int tid = blockIdx.x * 256 + threadIdx.x;            // grid 1024 -> 262144 threads
  u64* pmax = (u64*)((char*)wsf + pmax_off);
  u32* gmax = (u32*)((char*)wsf + gmax_off);
  if (tid < P * 16384) pmax[tid] = 0ull;
  if (tid < G * 4096)  gmax[tid] = 0u;
  if (tid < 131072){                                   // w5 [k=128][o=1024]
    int k = tid >> 10, o = tid & 1023;
    ((float*)((char*)wsf + w5_off))[tid] = wl4[o*128 + k];
  }
  if (tid < 512){ int k = tid >> 6, o = tid & 63;
    wsf[W0T + tid] = (k < 7) ? wl0[o*7 + k] : 0.f; }
  if (tid < 4096){ int k = tid >> 6, o = tid & 63;  wsf[W1T + tid] = wl1[o*64 + k]; }
  if (tid < 4096){ int k = tid >> 6, o = tid & 63;  wsf[W2T + tid] = wl2[o*64 + k]; }
  if (tid < 8192){ int k = tid >> 7, o = tid & 127; wsf[W3T + tid] = wl3[o*64 + k]; }
  if (tid < 64)   wsf[B0F + tid] = bl0[tid];
  if (tid < 64)   wsf[B1F + tid] = bl1[tid];
  if (tid < 64)   wsf[B2F + tid] = bl2[tid];
  if (tid < 128)  wsf[B3F + tid] = bl3[tid];
  if (tid < 1024) wsf[B4F + tid] = bl4[tid];
}

// 4pt x 4ch micro-tile; activations from LDS, weights from ws (L2-resident, broadcast)
template<int K, int OSTR>
__device__ __forceinline__ void gemm4(const float* Ain, const float* __restrict__ Wt,
                                      int pt4, int o4, f4* acc)
{
  #pragma unroll
  for (int oi = 0; oi < 4; ++oi) acc[oi] = f4{0.f,0.f,0.f,0.f};
  #pragma unroll 4
  for (int k = 0; k < K; ++k){
    f4 a = *(const f4*)(Ain + k*64 + pt4);
    f4 w = *(const f4*)(Wt + k*OSTR + o4);
    fma4(acc[0], w.x, a); fma4(acc[1], w.y, a);
    fma4(acc[2], w.z, a); fma4(acc[3], w.w, a);
  }
}

__device__ __forceinline__ void epi4(f4* acc, const float* __restrict__ bias,
                                     int o4, float* out, int pt4)
{
  #pragma unroll
  for (int oi = 0; oi < 4; ++oi){
    float bb = bias[o4 + oi];
    f4 v = acc[oi];
    v.x = fmaxf(v.x + bb, 0.f); v.y = fmaxf(v.y + bb, 0.f);
    v.z = fmaxf(v.z + bb, 0.f); v.w = fmaxf(v.w + bb, 0.f);
    *(f4*)(out + (o4 + oi)*64 + pt4) = v;
  }
}

// ---------------- fused local MLP (layers 0..4) + tile reductions ----------------
__global__ __launch_bounds__(256) void k_main(const float* __restrict__ pts, float* __restrict__ wsf,
    u32 pmax_off, u32 gmax_off, u32 w5_off, int pmask, int gmask)
{
  __shared__ __align__(16) float bufA[64*64];    // 16 KB
  __shared__ __align__(16) float bufB[128*64];   // 32 KB
  const int t = threadIdx.x;
  const int b = blockIdx.x >> 8;
  const int tile = blockIdx.x & 255;
  const int n0 = tile * 64;
  const int ptg = t & 15, pt4 = ptg << 2;
  const int chg = t >> 4;            // 0..15
  const int o4 = chg << 2;

  // stage A0 [7][64] fp32
  for (int e = t; e < 7*64; e += 256)
    bufB[e] = pts[(b*7 + (e >> 6))*NP + n0 + (e & 63)];
  __syncthreads();

  // group ids of my 4 points (argmax over channels 3..6, first occurrence)
  int gg[4];
  #pragma unroll
  for (int i = 0; i < 4; ++i){
    int p = pt4 + i;
    float v = bufB[3*64 + p]; int gi = 0;
    float u1 = bufB[4*64 + p]; if (u1 > v){ v = u1; gi = 1; }
    float u2 = bufB[5*64 + p]; if (u2 > v){ v = u2; gi = 2; }
    float u3 = bufB[6*64 + p]; if (u3 > v){ v = u3; gi = 3; }
    gg[i] = gi;
  }

  f4 acc[4];
  gemm4<7,64>(bufB, wsf + W0T, pt4, o4, acc);   epi4(acc, wsf + B0F, o4, bufA, pt4);  __syncthreads();
  gemm4<64,64>(bufA, wsf + W1T, pt4, o4, acc);  epi4(acc, wsf + B1F, o4, bufB, pt4);  __syncthreads();
  gemm4<64,64>(bufB, wsf + W2T, pt4, o4, acc);  epi4(acc, wsf + B2F, o4, bufA, pt4);  __syncthreads();
  gemm4<64,128>(bufA, wsf + W3T, pt4, o4, acc);      epi4(acc, wsf + B3F, o4, bufB, pt4);
  gemm4<64,128>(bufA, wsf + W3T, pt4, o4+64, acc);   epi4(acc, wsf + B3F, o4+64, bufB, pt4);
  __syncthreads();   // A4 [128][64] in bufB

  // ---- layer 4: 128 -> 1024, 8 chunks of 128 channels, micro 4pt x 8ch ----
  const int o8 = chg << 3;
  const float* w5f = (const float*)((const char*)wsf + w5_off);
  u64* pslot = (u64*)((char*)wsf + pmax_off) + (size_t)(tile & pmask)*(16*1024) + b*1024;
  u32* gslot = (u32*)((char*)wsf + gmax_off) + (size_t)(tile & gmask)*4096;

  for (int chunk = 0; chunk < 8; ++chunk){
    f4 a8[8];
    #pragma unroll
    for (int oi = 0; oi < 8; ++oi) a8[oi] = f4{0.f,0.f,0.f,0.f};
    #pragma unroll 4
    for (int k = 0; k < 128; ++k){
      f4 a = *(const f4*)(bufB + k*64 + pt4);
      const float* wp = w5f + (size_t)k*1024 + chunk*128 + o8;
      f4 w0 = *(const f4*)(wp);
      f4 w1 = *(const f4*)(wp + 4);
      fma4(a8[0], w0.x, a); fma4(a8[1], w0.y, a);
      fma4(a8[2], w0.z, a); fma4(a8[3], w0.w, a);
      fma4(a8[4], w1.x, a); fma4(a8[5], w1.y, a);
      fma4(a8[6], w1.z, a); fma4(a8[7], w1.w, a);
    }
    const int chbase = chunk*128 + o8;
    #pragma unroll
    for (int oi = 0; oi < 8; ++oi){
      float bb = wsf[B4F + chbase + oi];
      a8[oi].x = fmaxf(a8[oi].x + bb, 0.f);
      a8[oi].y = fmaxf(a8[oi].y + bb, 0.f);
      a8[oi].z = fmaxf(a8[oi].z + bb, 0.f);
      a8[oi].w = fmaxf(a8[oi].w + bb, 0.f);
    }
    // per-channel max+argmax over the 64-pt tile (first-occurrence ties)
    #pragma unroll
    for (int oi = 0; oi < 8; ++oi){
      float m = a8[oi].x; int idx = n0 + pt4;
      if (a8[oi].y > m){ m = a8[oi].y; idx = n0 + pt4 + 1; }
      if (a8[oi].z > m){ m = a8[oi].z; idx = n0 + pt4 + 2; }
      if (a8[oi].w > m){ m = a8[oi].w; idx = n0 + pt4 + 3; }
      #pragma unroll
      for (int off = 8; off >= 1; off >>= 1){
        float m2 = __shfl_down(m, off, 16);
        int  i2  = __shfl_down(idx, off, 16);
        if (m2 > m || (m2 == m && i2 < idx)){ m = m2; idx = i2; }
      }
      if (ptg == 0){
        u64 pk = ((u64)__float_as_uint(m) << 32) | (u64)(0xFFFFFFFFu - (u32)idx);
        atomicMax(pslot + chbase + oi, pk);
      }
    }
    // group-wise max (post-ReLU values >= 0; 0 = neutral/empty)
    #pragma unroll
    for (int gsel = 0; gsel < 4; ++gsel){
      #pragma unroll
      for (int oi = 0; oi < 8; ++oi){
        float gm = (gg[0] == gsel) ? a8[oi].x : 0.f;
        gm = fmaxf(gm, (gg[1] == gsel) ? a8[oi].y : 0.f);
        gm = fmaxf(gm, (gg[2] == gsel) ? a8[oi].z : 0.f);
        gm = fmaxf(gm, (gg[3] == gsel) ? a8[oi].w : 0.f);
        gm = fmaxf(gm, __shfl_down(gm, 8, 16));
        gm = fmaxf(gm, __shfl_down(gm, 4, 16));
        gm = fmaxf(gm, __shfl_down(gm, 2, 16));
        gm = fmaxf(gm, __shfl_down(gm, 1, 16));
        if (ptg == 0 && gm > 0.f)
          atomicMax(gslot + gsel*1024 + chbase + oi, __float_as_uint(gm));
      }
    }
  }
}

// ---------------- fold slots; emit max_indices (fp32) + gf + gcf ----------------
__global__ __launch_bounds__(256) void k_reduce(float* __restrict__ wsf, float* __restrict__ out,
                                                u32 pmax_off, u32 gmax_off, int P, int G)
{
  int e = blockIdx.x * 256 + threadIdx.x;          // grid 80 -> 20480
  u64* pmax = (u64*)((char*)wsf + pmax_off);
  u32* gmax = (u32*)((char*)wsf + gmax_off);
  if (e < 16384){
    u64 m = 0ull;
    for (int s = 0; s < P; ++s){ u64 v = pmax[s*16384 + e]; if (v > m) m = v; }
    float val = __uint_as_float((u32)(m >> 32));
    u32 idx = 0xFFFFFFFFu - (u32)(m & 0xFFFFFFFFull);
    wsf[GFO + e] = val;
    out[4096 + e] = (float)idx;                    // max_indices, fp32
  } else if (e < 20480){
    int e2 = e - 16384;
    u32 mg = 0u;
    for (int s = 0; s < G; ++s){ u32 v = gmax[s*4096 + e2]; if (v > mg) mg = v; }
    wsf[GCFO + e2] = __uint_as_float(mg);
  }
}

// ---------------- small MLPs: one wave per dot product ----------------
__global__ __launch_bounds__(256) void k_mlp1(float* __restrict__ wsf,
    const float* __restrict__ wg0, const float* __restrict__ bg0,
    const float* __restrict__ wgr0, const float* __restrict__ bgr0)
{
  int wid = (blockIdx.x * 256 + threadIdx.x) >> 6;   // grid 2176 -> 8704 waves
  int lane = threadIdx.x & 63;
  if (wid < 8192){                                   // of1 = relu(gf @ wg0^T + bg0)
    int b = wid >> 9, o = wid & 511;
    const float* gf = wsf + GFO + b*1024;
    float s = 0.f;
    #pragma unroll
    for (int i = 0; i < 16; ++i){ int k = lane + (i << 6); s = fmaf(gf[k], wg0[o*1024 + k], s); }
    for (int off = 32; off; off >>= 1) s += __shfl_down(s, off);
    if (lane == 0) wsf[OF1O + b*512 + o] = fmaxf(s + bg0[o], 0.f);
  } else if (wid < 8704){                            // gr1 = relu(gcf @ wgr0^T + bgr0)
    int o = wid - 8192;
    const float* gcf = wsf + GCFO;
    float s = 0.f;
    #pragma unroll 8
    for (int i = 0; i < 64; ++i){ int k = lane + (i << 6); s = fmaf(gcf[k], wgr0[o*4096 + k], s); }
    for (int off = 32; off; off >>= 1) s += __shfl_down(s, off);
    if (lane == 0) wsf[GR1O + o] = fmaxf(s + bgr0[o], 0.f);
  }
}

__global__ __launch_bounds__(256) void k_mlp2(const float* __restrict__ wsf,
    const float* __restrict__ wg1, const float* __restrict__ bg1,
    const float* __restrict__ wgr1, const float* __restrict__ bgr1,
    float* __restrict__ out)
{
  int wid = (blockIdx.x * 256 + threadIdx.x) >> 6;   // grid 544 -> 2176 waves
  int lane = threadIdx.x & 63;
  if (wid < 2048){                                   // output_feature -> feature[:,128:256]
    int b = wid >> 7, o = wid & 127;
    const float* of1 = wsf + OF1O + b*512;
    float s = 0.f;
    #pragma unroll
    for (int i = 0; i < 8; ++i){ int k = lane + (i << 6); s = fmaf(of1[k], wg1[o*512 + k], s); }
    for (int off = 32; off; off >>= 1) s += __shfl_down(s, off);
    if (lane == 0) out[b*256 + 128 + o] = fmaxf(s + bg1[o], 0.f);
  } else if (wid < 2176){                            // group_output_feature -> feature[:,0:128]
    int o = wid - 2048;
    const float* gr1 = wsf + GR1O;
    float s = 0.f;
    #pragma unroll
    for (int i = 0; i < 8; ++i){ int k = lane + (i << 6); s = fmaf(gr1[k], wgr1[o*512 + k], s); }
    for (int off = 32; off; off >>= 1) s += __shfl_down(s, off);
    if (lane == 0){
      float r = fmaxf(s + bgr1[o], 0.f);
      for (int bb = 0; bb < 16; ++bb) out[bb*256 + o] = r;   // identical across batch
    }
  }
}

extern "C" void kernel_launch(void* const* d_in, const int* in_sizes, int n_in,
                              void* d_out, int out_size, void* d_ws, size_t ws_size,
                              hipStream_t stream)
{
  const float* pts  = (const float*)d_in[0];
  const float* wl0  = (const float*)d_in[1];  const float* bl0 = (const float*)d_in[2];
  const float* wl1  = (const float*)d_in[3];  const float* bl1 = (const float*)d_in[4];
  const float* wl2  = (const float*)d_in[5];  const float* bl2 = (const float*)d_in[6];
  const float* wl3  = (const float*)d_in[7];  const float* bl3 = (const float*)d_in[8];
  const float* wl4  = (const float*)d_in[9];  const float* bl4 = (const float*)d_in[10];
  const float* wg0  = (const float*)d_in[11]; const float* bg0 = (const float*)d_in[12];
  const float* wg1  = (const float*)d_in[13]; const float* bg1 = (const float*)d_in[14];
  const float* wgr0 = (const float*)d_in[15]; const float* bgr0 = (const float*)d_in[16];
  const float* wgr1 = (const float*)d_in[17]; const float* bgr1 = (const float*)d_in[18];
  float* wsf = (float*)d_ws;
  float* out = (float*)d_out;

  // ws-size-adaptive: pmax P slots (128 KB), gmax G slots (16 KB), w5 fp32 (512 KB)
  int P, G;
  if      (ws_size >= 2600000) { P = 8; G = 16; }   // 2.02 MB
  else if (ws_size >= 1600000) { P = 4; G = 8;  }   // 1.37 MB
  else if (ws_size >= 1100000) { P = 2; G = 4;  }   // 1.04 MB
  else                         { P = 1; G = 2;  }   // 0.88 MB
  u32 pmax_off = FIXED_BYTES;
  u32 gmax_off = pmax_off + (u32)P * 131072u;
  u32 w5_off   = gmax_off + (u32)G * 16384u;

  k_prep<<<dim3(1024), dim3(256), 0, stream>>>(wl0, wl1, wl2, wl3, wl4,
      bl0, bl1, bl2, bl3, bl4, wsf, pmax_off, gmax_off, w5_off, P, G);
  k_main<<<dim3(4096), dim3(256), 0, stream>>>(pts, wsf, pmax_off, gmax_off, w5_off, P-1, G-1);
  k_reduce<<<dim3(80), dim3(256), 0, stream>>>(wsf, out, pmax_off, gmax_off, P, G);
  k_mlp1<<<dim3(2176), dim3(256), 0, stream>>>(wsf, wg0, bg0, wgr0, bgr0);
  k_mlp2<<<dim3(544), dim3(256), 0, stream>>>(wsf, wg1, bg1, wgr1, bgr1, out);
}

// Round 5
// 1191.282 us; speedup vs baseline: 1.3928x; 1.3928x over previous
//
#include <hip/hip_runtime.h>
#include <stdint.h>

typedef unsigned int u32;
typedef unsigned long long u64;

constexpr int NP = 16384;   // points per batch
// ---- fixed float-region offsets (in floats) ----
constexpr int W0T = 0;        // [8][64]   (k<7 valid, transposed)
constexpr int W1T = 512;      // [64][64]
constexpr int W2T = 4608;     // [64][64]
constexpr int W3T = 8704;     // [64][128]
constexpr int B0F = 16896, B1F = 16960, B2F = 17024, B3F = 17088, B4F = 17216;
constexpr int GFO = 18240;    // gf  [16][1024]
constexpr int GCFO = 34624;   // gcf [4][1024]
constexpr int OF1O = 38720;   // of1 [16][512]
constexpr int GR1O = 46912;   // gr1 [512]
constexpr int FIXED_FLOATS = 47424;
constexpr u32 FIXED_BYTES = FIXED_FLOATS * 4;   // 189696, 8B-aligned

struct __align__(16) f4 { float x, y, z, w; };

__device__ __forceinline__ void fma4(f4& c, float s, const f4& a){
  c.x = fmaf(s, a.x, c.x); c.y = fmaf(s, a.y, c.y);
  c.z = fmaf(s, a.z, c.z); c.w = fmaf(s, a.w, c.w);
}

// ---------------- prep: transpose weights to [k][o], zero reduce scratch ----------------
__global__ __launch_bounds__(256) void k_prep(
    const float* __restrict__ wl0, const float* __restrict__ wl1, const float* __restrict__ wl2,
    const float* __restrict__ wl3, const float* __restrict__ wl4,
    const float* __restrict__ bl0, const float* __restrict__ bl1, const float* __restrict__ bl2,
    const float* __restrict__ bl3, const float* __restrict__ bl4,
    float* __restrict__ wsf, u32 pmax_off, u32 gmax_off, u32 w5_off, int P, int G)
{
  int tid = blockIdx.x * 256 + threadIdx.x;            // grid 1024 -> 262144 threads
  u64* pmax = (u64*)((char*)wsf + pmax_off);
  u32* gmax = (u32*)((char*)wsf + gmax_off);
  if (tid < P * 16384) pmax[tid] = 0ull;
  if (tid < G * 4096)  gmax[tid] = 0u;
  if (tid < 131072){                                   // w5 [k=128][o=1024]
    int k = tid >> 10, o = tid & 1023;
    ((float*)((char*)wsf + w5_off))[tid] = wl4[o*128 + k];
  }
  if (tid < 512){ int k = tid >> 6, o = tid & 63;
    wsf[W0T + tid] = (k < 7) ? wl0[o*7 + k] : 0.f; }
  if (tid < 4096){ int k = tid >> 6, o = tid & 63;  wsf[W1T + tid] = wl1[o*64 + k]; }
  if (tid < 4096){ int k = tid >> 6, o = tid & 63;  wsf[W2T + tid] = wl2[o*64 + k]; }
  if (tid < 8192){ int k = tid >> 7, o = tid & 127; wsf[W3T + tid] = wl3[o*64 + k]; }
  if (tid < 64)   wsf[B0F + tid] = bl0[tid];
  if (tid < 64)   wsf[B1F + tid] = bl1[tid];
  if (tid < 64)   wsf[B2F + tid] = bl2[tid];
  if (tid < 128)  wsf[B3F + tid] = bl3[tid];
  if (tid < 1024) wsf[B4F + tid] = bl4[tid];
}

// 4pt x 4ch micro-tile for layers 0..3 (acts from LDS, weights from L2-resident ws)
template<int K, int OSTR>
__device__ __forceinline__ void gemm4(const float* Ain, const float* __restrict__ Wt,
                                      int pt4, int o4, f4* acc)
{
  #pragma unroll
  for (int oi = 0; oi < 4; ++oi) acc[oi] = f4{0.f,0.f,0.f,0.f};
  #pragma unroll 4
  for (int k = 0; k < K; ++k){
    f4 a = *(const f4*)(Ain + k*64 + pt4);
    f4 w = *(const f4*)(Wt + k*OSTR + o4);
    fma4(acc[0], w.x, a); fma4(acc[1], w.y, a);
    fma4(acc[2], w.z, a); fma4(acc[3], w.w, a);
  }
}

__device__ __forceinline__ void epi4(f4* acc, const float* __restrict__ bias,
                                     int o4, float* out, int pt4)
{
  #pragma unroll
  for (int oi = 0; oi < 4; ++oi){
    float bb = bias[o4 + oi];
    f4 v = acc[oi];
    v.x = fmaxf(v.x + bb, 0.f); v.y = fmaxf(v.y + bb, 0.f);
    v.z = fmaxf(v.z + bb, 0.f); v.w = fmaxf(v.w + bb, 0.f);
    *(f4*)(out + (o4 + oi)*64 + pt4) = v;
  }
}

// ---------------- fused local MLP (layers 0..4) + tile reductions ----------------
// Layer 4: lane = point, 32 channels/lane/pass in VGPRs, weights via wave-uniform
// scalar loads (s_load -> v_fmac v,s,v : zero per-k address VALU).
__global__ __launch_bounds__(256) void k_main(const float* __restrict__ pts,
    const float* __restrict__ wsf,
    const float* __restrict__ w5f,          // [128][1024] fp32
    const float* __restrict__ b4f,          // [1024]
    u64* __restrict__ pmax, u32* __restrict__ gmax,
    int pmask, int gmask)
{
  __shared__ __align__(16) float bufA[64*64];    // 16 KB : A1, A3, then redS [64ch][64pt]
  __shared__ __align__(16) float bufB[128*64];   // 32 KB : A0, A2, A4[k][pt]
  __shared__ u64 gmS[4];                         // per-group 64-bit point masks
  const int t = threadIdx.x;
  const int b = blockIdx.x >> 8;
  const int tile = blockIdx.x & 255;
  const int n0 = tile * 64;
  const int ptg = t & 15, pt4 = ptg << 2;
  const int chg = t >> 4;
  const int o4 = chg << 2;
  const int w = t >> 6;            // wave id 0..3
  const int lane = t & 63;
  const int laneq = t & 3;

  if (t < 4) gmS[t] = 0ull;
  // stage A0 [7][64] fp32
  for (int e = t; e < 7*64; e += 256)
    bufB[e] = pts[(b*7 + (e >> 6))*NP + n0 + (e & 63)];
  __syncthreads();

  // per-point group id (argmax ch 3..6, first occurrence) -> bitmasks in gmS
  if (t < 64){
    float v = bufB[3*64 + t]; int gi = 0;
    float u1 = bufB[4*64 + t]; if (u1 > v){ v = u1; gi = 1; }
    float u2 = bufB[5*64 + t]; if (u2 > v){ v = u2; gi = 2; }
    float u3 = bufB[6*64 + t]; if (u3 > v){ v = u3; gi = 3; }
    atomicOr(&gmS[gi], 1ull << t);
  }

  f4 acc4[4];
  gemm4<7,64>(bufB, wsf + W0T, pt4, o4, acc4);   epi4(acc4, wsf + B0F, o4, bufA, pt4);  __syncthreads();
  gemm4<64,64>(bufA, wsf + W1T, pt4, o4, acc4);  epi4(acc4, wsf + B1F, o4, bufB, pt4);  __syncthreads();
  gemm4<64,64>(bufB, wsf + W2T, pt4, o4, acc4);  epi4(acc4, wsf + B2F, o4, bufA, pt4);  __syncthreads();
  gemm4<64,128>(bufA, wsf + W3T, pt4, o4, acc4);      epi4(acc4, wsf + B3F, o4, bufB, pt4);
  gemm4<64,128>(bufA, wsf + W3T, pt4, o4+64, acc4);   epi4(acc4, wsf + B3F, o4+64, bufB, pt4);
  __syncthreads();   // A4 [128][64] in bufB; bufA now free for redS

  // 16-bit group masks for my 16-point segment (reduction role: q = t&3)
  u32 msk[4];
  #pragma unroll
  for (int g = 0; g < 4; ++g) msk[g] = (u32)((gmS[g] >> (laneq << 4)) & 0xFFFFull);

  u64* pslot = pmax + (size_t)(tile & pmask)*(16*1024) + b*1024;
  u32* gslot = gmax + (size_t)(tile & gmask)*4096;

  // ---- layer 4: 8 passes x (4 waves x 32 ch) = 1024 channels ----
  for (int p = 0; p < 8; ++p){
    const int cb = __builtin_amdgcn_readfirstlane((w << 8) + (p << 5));
    const float* __restrict__ wb = w5f + cb;    // wave-uniform -> s_load
    const float* __restrict__ bb = b4f + cb;
    float acc[32];
    #pragma unroll
    for (int o = 0; o < 32; ++o) acc[o] = 0.f;
    #pragma unroll 2
    for (int k = 0; k < 128; ++k){
      float a = bufB[(k << 6) + lane];
      #pragma unroll
      for (int o = 0; o < 32; ++o) acc[o] = fmaf(wb[(k << 10) + o], a, acc[o]);
    }
    #pragma unroll
    for (int half = 0; half < 2; ++half){
      // write my 16 channels' values for this point into redS [row=w*16+o2][pt]
      #pragma unroll
      for (int o2 = 0; o2 < 16; ++o2){
        int o = (half << 4) + o2;
        float v = fmaxf(acc[o] + bb[o], 0.f);
        bufA[(((w << 4) + o2) << 6) + lane] = v;
      }
      __syncthreads();
      // reduction: thread -> row r = t>>2 (channel), q = t&3 (16-pt segment)
      int r = t >> 2;
      const float* vp = bufA + (r << 6) + (laneq << 4);
      float va[16];
      *(f4*)(va + 0)  = *(const f4*)(vp + 0);
      *(f4*)(va + 4)  = *(const f4*)(vp + 4);
      *(f4*)(va + 8)  = *(const f4*)(vp + 8);
      *(f4*)(va + 12) = *(const f4*)(vp + 12);
      float m = va[0]; int idx = 0;
      #pragma unroll
      for (int i = 1; i < 16; ++i){ if (va[i] > m){ m = va[i]; idx = i; } }
      idx += n0 + (laneq << 4);
      float mg0 = 0.f, mg1 = 0.f, mg2 = 0.f, mg3 = 0.f;
      #pragma unroll
      for (int i = 0; i < 16; ++i){
        float vi = va[i];
        mg0 = fmaxf(mg0, ((msk[0] >> i) & 1) ? vi : 0.f);
        mg1 = fmaxf(mg1, ((msk[1] >> i) & 1) ? vi : 0.f);
        mg2 = fmaxf(mg2, ((msk[2] >> i) & 1) ? vi : 0.f);
        mg3 = fmaxf(mg3, ((msk[3] >> i) & 1) ? vi : 0.f);
      }
      #pragma unroll
      for (int s = 1; s < 4; s <<= 1){
        float m2 = __shfl_xor(m, s);
        int  i2  = __shfl_xor(idx, s);
        if (m2 > m || (m2 == m && i2 < idx)){ m = m2; idx = i2; }
        mg0 = fmaxf(mg0, __shfl_xor(mg0, s));
        mg1 = fmaxf(mg1, __shfl_xor(mg1, s));
        mg2 = fmaxf(mg2, __shfl_xor(mg2, s));
        mg3 = fmaxf(mg3, __shfl_xor(mg3, s));
      }
      __syncthreads();   // redS consumed; atomics issued after (drain overlaps next GEMM)
      if (laneq == 0){
        int ch = ((r >> 4) << 8) + (p << 5) + (half << 4) + (r & 15);
        u64 pk = ((u64)__float_as_uint(m) << 32) | (u64)(0xFFFFFFFFu - (u32)idx);
        atomicMax(pslot + ch, pk);
        if (mg0 > 0.f) atomicMax(gslot + ch,        __float_as_uint(mg0));
        if (mg1 > 0.f) atomicMax(gslot + 1024 + ch, __float_as_uint(mg1));
        if (mg2 > 0.f) atomicMax(gslot + 2048 + ch, __float_as_uint(mg2));
        if (mg3 > 0.f) atomicMax(gslot + 3072 + ch, __float_as_uint(mg3));
      }
    }
  }
}

// ---------------- fold slots; emit max_indices (fp32) + gf + gcf ----------------
__global__ __launch_bounds__(256) void k_reduce(float* __restrict__ wsf, float* __restrict__ out,
                                                u32 pmax_off, u32 gmax_off, int P, int G)
{
  int e = blockIdx.x * 256 + threadIdx.x;          // grid 80 -> 20480
  u64* pmax = (u64*)((char*)wsf + pmax_off);
  u32* gmax = (u32*)((char*)wsf + gmax_off);
  if (e < 16384){
    u64 m = 0ull;
    for (int s = 0; s < P; ++s){ u64 v = pmax[s*16384 + e]; if (v > m) m = v; }
    float val = __uint_as_float((u32)(m >> 32));
    u32 idx = 0xFFFFFFFFu - (u32)(m & 0xFFFFFFFFull);
    wsf[GFO + e] = val;
    out[4096 + e] = (float)idx;                    // max_indices, fp32
  } else if (e < 20480){
    int e2 = e - 16384;
    u32 mg = 0u;
    for (int s = 0; s < G; ++s){ u32 v = gmax[s*4096 + e2]; if (v > mg) mg = v; }
    wsf[GCFO + e2] = __uint_as_float(mg);
  }
}

// ---------------- small MLPs: one wave per dot product ----------------
__global__ __launch_bounds__(256) void k_mlp1(float* __restrict__ wsf,
    const float* __restrict__ wg0, const float* __restrict__ bg0,
    const float* __restrict__ wgr0, const float* __restrict__ bgr0)
{
  int wid = (blockIdx.x * 256 + threadIdx.x) >> 6;   // grid 2176 -> 8704 waves
  int lane = threadIdx.x & 63;
  if (wid < 8192){                                   // of1 = relu(gf @ wg0^T + bg0)
    int b = wid >> 9, o = wid & 511;
    const float* gf = wsf + GFO + b*1024;
    float s = 0.f;
    #pragma unroll
    for (int i = 0; i < 16; ++i){ int k = lane + (i << 6); s = fmaf(gf[k], wg0[o*1024 + k], s); }
    for (int off = 32; off; off >>= 1) s += __shfl_down(s, off);
    if (lane == 0) wsf[OF1O + b*512 + o] = fmaxf(s + bg0[o], 0.f);
  } else if (wid < 8704){                            // gr1 = relu(gcf @ wgr0^T + bgr0)
    int o = wid - 8192;
    const float* gcf = wsf + GCFO;
    float s = 0.f;
    #pragma unroll 8
    for (int i = 0; i < 64; ++i){ int k = lane + (i << 6); s = fmaf(gcf[k], wgr0[o*4096 + k], s); }
    for (int off = 32; off; off >>= 1) s += __shfl_down(s, off);
    if (lane == 0) wsf[GR1O + o] = fmaxf(s + bgr0[o], 0.f);
  }
}

__global__ __launch_bounds__(256) void k_mlp2(const float* __restrict__ wsf,
    const float* __restrict__ wg1, const float* __restrict__ bg1,
    const float* __restrict__ wgr1, const float* __restrict__ bgr1,
    float* __restrict__ out)
{
  int wid = (blockIdx.x * 256 + threadIdx.x) >> 6;   // grid 544 -> 2176 waves
  int lane = threadIdx.x & 63;
  if (wid < 2048){                                   // output_feature -> feature[:,128:256]
    int b = wid >> 7, o = wid & 127;
    const float* of1 = wsf + OF1O + b*512;
    float s = 0.f;
    #pragma unroll
    for (int i = 0; i < 8; ++i){ int k = lane + (i << 6); s = fmaf(of1[k], wg1[o*512 + k], s); }
    for (int off = 32; off; off >>= 1) s += __shfl_down(s, off);
    if (lane == 0) out[b*256 + 128 + o] = fmaxf(s + bg1[o], 0.f);
  } else if (wid < 2176){                            // group_output_feature -> feature[:,0:128]
    int o = wid - 2048;
    const float* gr1 = wsf + GR1O;
    float s = 0.f;
    #pragma unroll
    for (int i = 0; i < 8; ++i){ int k = lane + (i << 6); s = fmaf(gr1[k], wgr1[o*512 + k], s); }
    for (int off = 32; off; off >>= 1) s += __shfl_down(s, off);
    if (lane == 0){
      float r = fmaxf(s + bgr1[o], 0.f);
      for (int bb = 0; bb < 16; ++bb) out[bb*256 + o] = r;   // identical across batch
    }
  }
}

extern "C" void kernel_launch(void* const* d_in, const int* in_sizes, int n_in,
                              void* d_out, int out_size, void* d_ws, size_t ws_size,
                              hipStream_t stream)
{
  const float* pts  = (const float*)d_in[0];
  const float* wl0  = (const float*)d_in[1];  const float* bl0 = (const float*)d_in[2];
  const float* wl1  = (const float*)d_in[3];  const float* bl1 = (const float*)d_in[4];
  const float* wl2  = (const float*)d_in[5];  const float* bl2 = (const float*)d_in[6];
  const float* wl3  = (const float*)d_in[7];  const float* bl3 = (const float*)d_in[8];
  const float* wl4  = (const float*)d_in[9];  const float* bl4 = (const float*)d_in[10];
  const float* wg0  = (const float*)d_in[11]; const float* bg0 = (const float*)d_in[12];
  const float* wg1  = (const float*)d_in[13]; const float* bg1 = (const float*)d_in[14];
  const float* wgr0 = (const float*)d_in[15]; const float* bgr0 = (const float*)d_in[16];
  const float* wgr1 = (const float*)d_in[17]; const float* bgr1 = (const float*)d_in[18];
  float* wsf = (float*)d_ws;
  float* out = (float*)d_out;

  // ws-size-adaptive: pmax P slots (128 KB), gmax G slots (16 KB), w5 fp32 (512 KB)
  int P, G;
  if      (ws_size >= 2600000) { P = 8; G = 16; }   // 2.02 MB
  else if (ws_size >= 1600000) { P = 4; G = 8;  }   // 1.37 MB
  else if (ws_size >= 1100000) { P = 2; G = 4;  }   // 1.04 MB
  else                         { P = 1; G = 2;  }   // 0.88 MB
  u32 pmax_off = FIXED_BYTES;
  u32 gmax_off = pmax_off + (u32)P * 131072u;
  u32 w5_off   = gmax_off + (u32)G * 16384u;

  k_prep<<<dim3(1024), dim3(256), 0, stream>>>(wl0, wl1, wl2, wl3, wl4,
      bl0, bl1, bl2, bl3, bl4, wsf, pmax_off, gmax_off, w5_off, P, G);
  k_main<<<dim3(4096), dim3(256), 0, stream>>>(pts, wsf,
      (const float*)((char*)d_ws + w5_off), wsf + B4F,
      (u64*)((char*)d_ws + pmax_off), (u32*)((char*)d_ws + gmax_off), P-1, G-1);
  k_reduce<<<dim3(80), dim3(256), 0, stream>>>(wsf, out, pmax_off, gmax_off, P, G);
  k_mlp1<<<dim3(2176), dim3(256), 0, stream>>>(wsf, wg0, bg0, wgr0, bgr0);
  k_mlp2<<<dim3(544), dim3(256), 0, stream>>>(wsf, wg1, bg1, wgr1, bgr1, out);
}

// Round 6
// 1180.323 us; speedup vs baseline: 1.4057x; 1.0093x over previous
//
#include <hip/hip_runtime.h>
#include <stdint.h>

typedef unsigned int u32;
typedef unsigned long long u64;
typedef float v2f __attribute__((ext_vector_type(2)));

constexpr int NP = 16384;   // points per batch
// ---- fixed float-region offsets (in floats) ----
constexpr int W0T = 0;        // [8][64]   (k<7 valid, transposed)
constexpr int W1T = 512;      // [64][64]
constexpr int W2T = 4608;     // [64][64]
constexpr int W3T = 8704;     // [64][128]
constexpr int B0F = 16896, B1F = 16960, B2F = 17024, B3F = 17088, B4F = 17216;
constexpr int GFO = 18240;    // gf  [16][1024]
constexpr int GCFO = 34624;   // gcf [4][1024]
constexpr int OF1O = 38720;   // of1 [16][512]
constexpr int GR1O = 46912;   // gr1 [512]
constexpr int FIXED_FLOATS = 47424;
constexpr u32 FIXED_BYTES = FIXED_FLOATS * 4;   // 189696, 8B-aligned

struct __align__(16) f4 { float x, y, z, w; };

__device__ __forceinline__ void fma4(f4& c, float s, const f4& a){
  c.x = fmaf(s, a.x, c.x); c.y = fmaf(s, a.y, c.y);
  c.z = fmaf(s, a.z, c.z); c.w = fmaf(s, a.w, c.w);
}

// ---------------- prep: transpose weights, zero reduce scratch ----------------
// w5 packed as W5P[k2=64][ch=1024][2]  (k-pair interleaved for v_pk_fma_f32)
__global__ __launch_bounds__(256) void k_prep(
    const float* __restrict__ wl0, const float* __restrict__ wl1, const float* __restrict__ wl2,
    const float* __restrict__ wl3, const float* __restrict__ wl4,
    const float* __restrict__ bl0, const float* __restrict__ bl1, const float* __restrict__ bl2,
    const float* __restrict__ bl3, const float* __restrict__ bl4,
    float* __restrict__ wsf, u32 pmax_off, u32 gmax_off, u32 w5_off, int P, int G)
{
  int tid = blockIdx.x * 256 + threadIdx.x;            // grid 1024 -> 262144 threads
  u64* pmax = (u64*)((char*)wsf + pmax_off);
  u32* gmax = (u32*)((char*)wsf + gmax_off);
  if (tid < P * 16384) pmax[tid] = 0ull;
  if (tid < G * 4096)  gmax[tid] = 0u;
  if (tid < 131072){                                   // W5P [k2][o][2]
    int k2 = tid >> 11, o = (tid >> 1) & 1023, j = tid & 1;
    ((float*)((char*)wsf + w5_off))[tid] = wl4[o*128 + (k2 << 1) + j];
  }
  if (tid < 512){ int k = tid >> 6, o = tid & 63;
    wsf[W0T + tid] = (k < 7) ? wl0[o*7 + k] : 0.f; }
  if (tid < 4096){ int k = tid >> 6, o = tid & 63;  wsf[W1T + tid] = wl1[o*64 + k]; }
  if (tid < 4096){ int k = tid >> 6, o = tid & 63;  wsf[W2T + tid] = wl2[o*64 + k]; }
  if (tid < 8192){ int k = tid >> 7, o = tid & 127; wsf[W3T + tid] = wl3[o*64 + k]; }
  if (tid < 64)   wsf[B0F + tid] = bl0[tid];
  if (tid < 64)   wsf[B1F + tid] = bl1[tid];
  if (tid < 64)   wsf[B2F + tid] = bl2[tid];
  if (tid < 128)  wsf[B3F + tid] = bl3[tid];
  if (tid < 1024) wsf[B4F + tid] = bl4[tid];
}

// 4pt x 4ch micro-tile for layers 0..3 (acts from LDS, weights from L2-resident ws)
template<int K, int OSTR>
__device__ __forceinline__ void gemm4(const float* Ain, const float* __restrict__ Wt,
                                      int pt4, int o4, f4* acc)
{
  #pragma unroll
  for (int oi = 0; oi < 4; ++oi) acc[oi] = f4{0.f,0.f,0.f,0.f};
  #pragma unroll 4
  for (int k = 0; k < K; ++k){
    f4 a = *(const f4*)(Ain + k*64 + pt4);
    f4 w = *(const f4*)(Wt + k*OSTR + o4);
    fma4(acc[0], w.x, a); fma4(acc[1], w.y, a);
    fma4(acc[2], w.z, a); fma4(acc[3], w.w, a);
  }
}

__device__ __forceinline__ void epi4(f4* acc, const float* __restrict__ bias,
                                     int o4, float* out, int pt4)
{
  #pragma unroll
  for (int oi = 0; oi < 4; ++oi){
    float bb = bias[o4 + oi];
    f4 v = acc[oi];
    v.x = fmaxf(v.x + bb, 0.f); v.y = fmaxf(v.y + bb, 0.f);
    v.z = fmaxf(v.z + bb, 0.f); v.w = fmaxf(v.w + bb, 0.f);
    *(f4*)(out + (o4 + oi)*64 + pt4) = v;
  }
}

// ---------------- fused local MLP (layers 0..4) + tile reductions ----------------
// Layer 4: lane = point, 32 ch/lane/pass; K packed in pairs -> v_pk_fma_f32
// (weights = wave-uniform SGPR pairs from packed [k2][ch][2] layout; acts via ds_read2).
// redS stride 68 floats: start bank = 4r+16q -> uniform 8 accesses/bank (conflict-free).
__global__ __launch_bounds__(256) void k_main(const float* __restrict__ pts,
    const float* __restrict__ wsf,
    const float* __restrict__ w5f,          // W5P [64][1024][2] fp32
    const float* __restrict__ b4f,          // [1024]
    u64* __restrict__ pmax, u32* __restrict__ gmax,
    int pmask, int gmask)
{
  __shared__ __align__(16) float bufA[64*68];    // 17 KB : A1/A3 (stride 64), redS (stride 68)
  __shared__ __align__(16) float bufB[128*64];   // 32 KB : A0, A2, A4[k][pt]
  __shared__ u64 gmS[4];                         // per-group 64-bit point masks
  const int t = threadIdx.x;
  const int b = blockIdx.x >> 8;
  const int tile = blockIdx.x & 255;
  const int n0 = tile * 64;
  const int ptg = t & 15, pt4 = ptg << 2;
  const int chg = t >> 4;
  const int o4 = chg << 2;
  const int w = t >> 6;            // wave id 0..3
  const int lane = t & 63;
  const int laneq = t & 3;

  if (t < 4) gmS[t] = 0ull;
  // stage A0 [7][64] fp32
  for (int e = t; e < 7*64; e += 256)
    bufB[e] = pts[(b*7 + (e >> 6))*NP + n0 + (e & 63)];
  __syncthreads();

  // per-point group id (argmax ch 3..6, first occurrence) -> bitmasks in gmS
  if (t < 64){
    float v = bufB[3*64 + t]; int gi = 0;
    float u1 = bufB[4*64 + t]; if (u1 > v){ v = u1; gi = 1; }
    float u2 = bufB[5*64 + t]; if (u2 > v){ v = u2; gi = 2; }
    float u3 = bufB[6*64 + t]; if (u3 > v){ v = u3; gi = 3; }
    atomicOr(&gmS[gi], 1ull << t);
  }

  f4 acc4[4];
  gemm4<7,64>(bufB, wsf + W0T, pt4, o4, acc4);   epi4(acc4, wsf + B0F, o4, bufA, pt4);  __syncthreads();
  gemm4<64,64>(bufA, wsf + W1T, pt4, o4, acc4);  epi4(acc4, wsf + B1F, o4, bufB, pt4);  __syncthreads();
  gemm4<64,64>(bufB, wsf + W2T, pt4, o4, acc4);  epi4(acc4, wsf + B2F, o4, bufA, pt4);  __syncthreads();
  gemm4<64,128>(bufA, wsf + W3T, pt4, o4, acc4);      epi4(acc4, wsf + B3F, o4, bufB, pt4);
  gemm4<64,128>(bufA, wsf + W3T, pt4, o4+64, acc4);   epi4(acc4, wsf + B3F, o4+64, bufB, pt4);
  __syncthreads();   // A4 [128][64] in bufB; bufA now free for redS

  // 16-bit group masks for my 16-point segment (reduction role: q = t&3)
  u32 msk[4];
  #pragma unroll
  for (int g = 0; g < 4; ++g) msk[g] = (u32)((gmS[g] >> (laneq << 4)) & 0xFFFFull);

  u64* pslot = pmax + (size_t)(tile & pmask)*(16*1024) + b*1024;
  u32* gslot = gmax + (size_t)(tile & gmask)*4096;

  // ---- layer 4: 8 passes x (4 waves x 32 ch) = 1024 channels, K in pairs ----
  for (int p = 0; p < 8; ++p){
    const int cb = __builtin_amdgcn_readfirstlane((w << 8) + (p << 5));
    const v2f* __restrict__ w2p = (const v2f*)w5f + cb;   // pair idx = k2*1024 + ch
    const float* __restrict__ bb = b4f + cb;
    v2f acc2[32];
    #pragma unroll
    for (int o = 0; o < 32; ++o) acc2[o] = (v2f)(0.f);
    #pragma unroll 2
    for (int k2 = 0; k2 < 64; ++k2){
      v2f a2;
      a2.x = bufB[(k2 << 7) + lane];          // k = 2*k2
      a2.y = bufB[(k2 << 7) + 64 + lane];     // k = 2*k2+1  (ds_read2_b32 pair)
      const v2f* __restrict__ wk = w2p + (k2 << 10);
      #pragma unroll
      for (int o = 0; o < 32; ++o)
        acc2[o] = __builtin_elementwise_fma(wk[o], a2, acc2[o]);   // v_pk_fma_f32
    }
    float accs[32];
    #pragma unroll
    for (int o = 0; o < 32; ++o) accs[o] = acc2[o].x + acc2[o].y;

    #pragma unroll
    for (int half = 0; half < 2; ++half){
      // write my 16 channels' values for this point into redS [row=w*16+o2][pt], stride 68
      #pragma unroll
      for (int o2 = 0; o2 < 16; ++o2){
        int o = (half << 4) + o2;
        float v = fmaxf(accs[o] + bb[o], 0.f);
        bufA[((w << 4) + o2) * 68 + lane] = v;
      }
      __syncthreads();
      // reduction: thread -> row r = t>>2 (channel), q = t&3 (16-pt segment)
      int r = t >> 2;
      const float* vp = bufA + r * 68 + (laneq << 4);
      float va[16];
      *(f4*)(va + 0)  = *(const f4*)(vp + 0);
      *(f4*)(va + 4)  = *(const f4*)(vp + 4);
      *(f4*)(va + 8)  = *(const f4*)(vp + 8);
      *(f4*)(va + 12) = *(const f4*)(vp + 12);
      float m = va[0]; int idx = 0;
      #pragma unroll
      for (int i = 1; i < 16; ++i){ if (va[i] > m){ m = va[i]; idx = i; } }
      idx += n0 + (laneq << 4);
      float mg0 = 0.f, mg1 = 0.f, mg2 = 0.f, mg3 = 0.f;
      #pragma unroll
      for (int i = 0; i < 16; ++i){
        float vi = va[i];
        mg0 = fmaxf(mg0, ((msk[0] >> i) & 1) ? vi : 0.f);
        mg1 = fmaxf(mg1, ((msk[1] >> i) & 1) ? vi : 0.f);
        mg2 = fmaxf(mg2, ((msk[2] >> i) & 1) ? vi : 0.f);
        mg3 = fmaxf(mg3, ((msk[3] >> i) & 1) ? vi : 0.f);
      }
      #pragma unroll
      for (int s = 1; s < 4; s <<= 1){
        float m2 = __shfl_xor(m, s);
        int  i2  = __shfl_xor(idx, s);
        if (m2 > m || (m2 == m && i2 < idx)){ m = m2; idx = i2; }
        mg0 = fmaxf(mg0, __shfl_xor(mg0, s));
        mg1 = fmaxf(mg1, __shfl_xor(mg1, s));
        mg2 = fmaxf(mg2, __shfl_xor(mg2, s));
        mg3 = fmaxf(mg3, __shfl_xor(mg3, s));
      }
      __syncthreads();   // redS consumed; atomics issued after (drain overlaps next pass)
      if (laneq == 0){
        int ch = ((r >> 4) << 8) + (p << 5) + (half << 4) + (r & 15);
        u64 pk = ((u64)__float_as_uint(m) << 32) | (u64)(0xFFFFFFFFu - (u32)idx);
        atomicMax(pslot + ch, pk);
        if (mg0 > 0.f) atomicMax(gslot + ch,        __float_as_uint(mg0));
        if (mg1 > 0.f) atomicMax(gslot + 1024 + ch, __float_as_uint(mg1));
        if (mg2 > 0.f) atomicMax(gslot + 2048 + ch, __float_as_uint(mg2));
        if (mg3 > 0.f) atomicMax(gslot + 3072 + ch, __float_as_uint(mg3));
      }
    }
  }
}

// ---------------- fold slots; emit max_indices (fp32) + gf + gcf ----------------
__global__ __launch_bounds__(256) void k_reduce(float* __restrict__ wsf, float* __restrict__ out,
                                                u32 pmax_off, u32 gmax_off, int P, int G)
{
  int e = blockIdx.x * 256 + threadIdx.x;          // grid 80 -> 20480
  u64* pmax = (u64*)((char*)wsf + pmax_off);
  u32* gmax = (u32*)((char*)wsf + gmax_off);
  if (e < 16384){
    u64 m = 0ull;
    for (int s = 0; s < P; ++s){ u64 v = pmax[s*16384 + e]; if (v > m) m = v; }
    float val = __uint_as_float((u32)(m >> 32));
    u32 idx = 0xFFFFFFFFu - (u32)(m & 0xFFFFFFFFull);
    wsf[GFO + e] = val;
    out[4096 + e] = (float)idx;                    // max_indices, fp32
  } else if (e < 20480){
    int e2 = e - 16384;
    u32 mg = 0u;
    for (int s = 0; s < G; ++s){ u32 v = gmax[s*4096 + e2]; if (v > mg) mg = v; }
    wsf[GCFO + e2] = __uint_as_float(mg);
  }
}

// ---------------- small MLPs: one wave per dot product ----------------
__global__ __launch_bounds__(256) void k_mlp1(float* __restrict__ wsf,
    const float* __restrict__ wg0, const float* __restrict__ bg0,
    const float* __restrict__ wgr0, const float* __restrict__ bgr0)
{
  int wid = (blockIdx.x * 256 + threadIdx.x) >> 6;   // grid 2176 -> 8704 waves
  int lane = threadIdx.x & 63;
  if (wid < 8192){                                   // of1 = relu(gf @ wg0^T + bg0)
    int b = wid >> 9, o = wid & 511;
    const float* gf = wsf + GFO + b*1024;
    float s = 0.f;
    #pragma unroll
    for (int i = 0; i < 16; ++i){ int k = lane + (i << 6); s = fmaf(gf[k], wg0[o*1024 + k], s); }
    for (int off = 32; off; off >>= 1) s += __shfl_down(s, off);
    if (lane == 0) wsf[OF1O + b*512 + o] = fmaxf(s + bg0[o], 0.f);
  } else if (wid < 8704){                            // gr1 = relu(gcf @ wgr0^T + bgr0)
    int o = wid - 8192;
    const float* gcf = wsf + GCFO;
    float s = 0.f;
    #pragma unroll 8
    for (int i = 0; i < 64; ++i){ int k = lane + (i << 6); s = fmaf(gcf[k], wgr0[o*4096 + k], s); }
    for (int off = 32; off; off >>= 1) s += __shfl_down(s, off);
    if (lane == 0) wsf[GR1O + o] = fmaxf(s + bgr0[o], 0.f);
  }
}

__global__ __launch_bounds__(256) void k_mlp2(const float* __restrict__ wsf,
    const float* __restrict__ wg1, const float* __restrict__ bg1,
    const float* __restrict__ wgr1, const float* __restrict__ bgr1,
    float* __restrict__ out)
{
  int wid = (blockIdx.x * 256 + threadIdx.x) >> 6;   // grid 544 -> 2176 waves
  int lane = threadIdx.x & 63;
  if (wid < 2048){                                   // output_feature -> feature[:,128:256]
    int b = wid >> 7, o = wid & 127;
    const float* of1 = wsf + OF1O + b*512;
    float s = 0.f;
    #pragma unroll
    for (int i = 0; i < 8; ++i){ int k = lane + (i << 6); s = fmaf(of1[k], wg1[o*512 + k], s); }
    for (int off = 32; off; off >>= 1) s += __shfl_down(s, off);
    if (lane == 0) out[b*256 + 128 + o] = fmaxf(s + bg1[o], 0.f);
  } else if (wid < 2176){                            // group_output_feature -> feature[:,0:128]
    int o = wid - 2048;
    const float* gr1 = wsf + GR1O;
    float s = 0.f;
    #pragma unroll
    for (int i = 0; i < 8; ++i){ int k = lane + (i << 6); s = fmaf(gr1[k], wgr1[o*512 + k], s); }
    for (int off = 32; off; off >>= 1) s += __shfl_down(s, off);
    if (lane == 0){
      float r = fmaxf(s + bgr1[o], 0.f);
      for (int bb = 0; bb < 16; ++bb) out[bb*256 + o] = r;   // identical across batch
    }
  }
}

extern "C" void kernel_launch(void* const* d_in, const int* in_sizes, int n_in,
                              void* d_out, int out_size, void* d_ws, size_t ws_size,
                              hipStream_t stream)
{
  const float* pts  = (const float*)d_in[0];
  const float* wl0  = (const float*)d_in[1];  const float* bl0 = (const float*)d_in[2];
  const float* wl1  = (const float*)d_in[3];  const float* bl1 = (const float*)d_in[4];
  const float* wl2  = (const float*)d_in[5];  const float* bl2 = (const float*)d_in[6];
  const float* wl3  = (const float*)d_in[7];  const float* bl3 = (const float*)d_in[8];
  const float* wl4  = (const float*)d_in[9];  const float* bl4 = (const float*)d_in[10];
  const float* wg0  = (const float*)d_in[11]; const float* bg0 = (const float*)d_in[12];
  const float* wg1  = (const float*)d_in[13]; const float* bg1 = (const float*)d_in[14];
  const float* wgr0 = (const float*)d_in[15]; const float* bgr0 = (const float*)d_in[16];
  const float* wgr1 = (const float*)d_in[17]; const float* bgr1 = (const float*)d_in[18];
  float* wsf = (float*)d_ws;
  float* out = (float*)d_out;

  // ws-size-adaptive: pmax P slots (128 KB), gmax G slots (16 KB), w5p fp32 (512 KB)
  int P, G;
  if      (ws_size >= 2600000) { P = 8; G = 16; }   // 2.02 MB
  else if (ws_size >= 1600000) { P = 4; G = 8;  }   // 1.37 MB
  else if (ws_size >= 1100000) { P = 2; G = 4;  }   // 1.04 MB
  else                         { P = 1; G = 2;  }   // 0.88 MB
  u32 pmax_off = FIXED_BYTES;
  u32 gmax_off = pmax_off + (u32)P * 131072u;
  u32 w5_off   = gmax_off + (u32)G * 16384u;

  k_prep<<<dim3(1024), dim3(256), 0, stream>>>(wl0, wl1, wl2, wl3, wl4,
      bl0, bl1, bl2, bl3, bl4, wsf, pmax_off, gmax_off, w5_off, P, G);
  k_main<<<dim3(4096), dim3(256), 0, stream>>>(pts, wsf,
      (const float*)((char*)d_ws + w5_off), wsf + B4F,
      (u64*)((char*)d_ws + pmax_off), (u32*)((char*)d_ws + gmax_off), P-1, G-1);
  k_reduce<<<dim3(80), dim3(256), 0, stream>>>(wsf, out, pmax_off, gmax_off, P, G);
  k_mlp1<<<dim3(2176), dim3(256), 0, stream>>>(wsf, wg0, bg0, wgr0, bgr0);
  k_mlp2<<<dim3(544), dim3(256), 0, stream>>>(wsf, wg1, bg1, wgr1, bgr1, out);
}

// Round 7
// 670.845 us; speedup vs baseline: 2.4733x; 1.7595x over previous
//
#include <hip/hip_runtime.h>
#include <stdint.h>

typedef unsigned int u32;
typedef unsigned long long u64;
typedef unsigned short u16b;
typedef __attribute__((ext_vector_type(8))) short short8;   // 8 bf16 = 4 VGPR (MFMA A/B frag)
typedef __attribute__((ext_vector_type(4))) float v4f;      // MFMA C/D frag

constexpr int NP = 16384;   // points per batch
// ---- fixed float-region offsets (in floats) ----
constexpr int W0T = 0;        // [8][64]
constexpr int W1T = 512;      // [64][64]
constexpr int W2T = 4608;     // [64][64]
constexpr int W3T = 8704;     // [64][128]
constexpr int B0F = 16896, B1F = 16960, B2F = 17024, B3F = 17088, B4F = 17216;
constexpr int GFO = 18240;    // gf  [16][1024]
constexpr int GCFO = 34624;   // gcf [4][1024]
constexpr int OF1O = 38720;   // of1 [16][512]
constexpr int GR1O = 46912;   // gr1 [512]
constexpr int FIXED_FLOATS = 47424;
constexpr u32 FIXED_BYTES = FIXED_FLOATS * 4;   // 189696 B

struct __align__(16) f4 { float x, y, z, w; };

__device__ __forceinline__ u16b f2bf(float f){
  u32 u = __float_as_uint(f);
  return (u16b)((u + 0x7FFFu + ((u >> 16) & 1u)) >> 16);   // RNE
}
__device__ __forceinline__ float bfu(u16b h){ return __uint_as_float(((u32)h) << 16); }

// exact-cascade 3-way bf16 split: x ~= hi+mid+lo to ~27 bits
__device__ __forceinline__ void split3(float x, u16b& h, u16b& m, u16b& l){
  h = f2bf(x);           float r1 = x - bfu(h);
  m = f2bf(r1);          float r2 = r1 - bfu(m);
  l = f2bf(r2);
}

__device__ __forceinline__ void fma4(f4& c, float s, const f4& a){
  c.x = fmaf(s, a.x, c.x); c.y = fmaf(s, a.y, c.y);
  c.z = fmaf(s, a.z, c.z); c.w = fmaf(s, a.w, c.w);
}

// ---------------- prep: transpose L0-3 weights; split+frag-pack W5 to bf16x3 ----------------
// Wb layout (bf16): [s][kc][nt][lane][j]  addr = s*131072 + kc*32768 + nt*512 + L*8 + j
// consumer: B[k=kc*32+(L>>4)*8+j][ch=nt*16+(L&15)]  (MFMA B-frag, 16 B/lane coalesced)
__global__ __launch_bounds__(256) void k_prep(
    const float* __restrict__ wl0, const float* __restrict__ wl1, const float* __restrict__ wl2,
    const float* __restrict__ wl3, const float* __restrict__ wl4,
    const float* __restrict__ bl0, const float* __restrict__ bl1, const float* __restrict__ bl2,
    const float* __restrict__ bl3, const float* __restrict__ bl4,
    float* __restrict__ wsf, u32 pmax_off, u32 gmax_off, u32 wb_off, int P, int G)
{
  int tid = blockIdx.x * 256 + threadIdx.x;            // grid 1024 -> 262144 threads
  u64* pmax = (u64*)((char*)wsf + pmax_off);
  u32* gmax = (u32*)((char*)wsf + gmax_off);
  if (tid < P * 16384) pmax[tid] = 0ull;
  if (tid < G * 4096)  gmax[tid] = 0u;
  if (tid < 131072){                                   // W5 split -> Wb
    int ch = tid >> 7, k = tid & 127;
    float x = wl4[tid];                                // wl4[ch*128 + k]
    u16b h, m, l; split3(x, h, m, l);
    int kc = k >> 5, q = (k >> 3) & 3, j = k & 7, nt = ch >> 4;
    u32 base = (u32)kc*32768u + (u32)nt*512u + (u32)(((ch & 15) | (q << 4)) * 8 + j);
    u16b* wb = (u16b*)((char*)wsf + wb_off);
    wb[base] = h; wb[131072u + base] = m; wb[262144u + base] = l;
  }
  if (tid < 512){ int k = tid >> 6, o = tid & 63;
    wsf[W0T + tid] = (k < 7) ? wl0[o*7 + k] : 0.f; }
  if (tid < 4096){ int k = tid >> 6, o = tid & 63;  wsf[W1T + tid] = wl1[o*64 + k]; }
  if (tid < 4096){ int k = tid >> 6, o = tid & 63;  wsf[W2T + tid] = wl2[o*64 + k]; }
  if (tid < 8192){ int k = tid >> 7, o = tid & 127; wsf[W3T + tid] = wl3[o*64 + k]; }
  if (tid < 64)   wsf[B0F + tid] = bl0[tid];
  if (tid < 64)   wsf[B1F + tid] = bl1[tid];
  if (tid < 64)   wsf[B2F + tid] = bl2[tid];
  if (tid < 128)  wsf[B3F + tid] = bl3[tid];
  if (tid < 1024) wsf[B4F + tid] = bl4[tid];
}

// 4pt x 4ch micro-tile for layers 0..3 (acts from LDS, weights from L2-resident ws)
template<int K, int OSTR>
__device__ __forceinline__ void gemm4(const float* Ain, const float* __restrict__ Wt,
                                      int pt4, int o4, f4* acc)
{
  #pragma unroll
  for (int oi = 0; oi < 4; ++oi) acc[oi] = f4{0.f,0.f,0.f,0.f};
  #pragma unroll 4
  for (int k = 0; k < K; ++k){
    f4 a = *(const f4*)(Ain + k*64 + pt4);
    f4 w = *(const f4*)(Wt + k*OSTR + o4);
    fma4(acc[0], w.x, a); fma4(acc[1], w.y, a);
    fma4(acc[2], w.z, a); fma4(acc[3], w.w, a);
  }
}

__device__ __forceinline__ void epi4(f4* acc, const float* __restrict__ bias,
                                     int o4, float* out, int pt4)
{
  #pragma unroll
  for (int oi = 0; oi < 4; ++oi){
    float bb = bias[o4 + oi];
    f4 v = acc[oi];
    v.x = fmaxf(v.x + bb, 0.f); v.y = fmaxf(v.y + bb, 0.f);
    v.z = fmaxf(v.z + bb, 0.f); v.w = fmaxf(v.w + bb, 0.f);
    *(f4*)(out + (o4 + oi)*64 + pt4) = v;
  }
}

// ---------------- fused local MLP: L0-3 fp32 VALU, L4 bf16-split3 MFMA ----------------
// LDS: sA 16 KB (A1/A3, then bias), sB 48 KB (A0/A2, then A-frag splits). 64 KB -> 2 blk/CU.
__global__ __launch_bounds__(256, 2) void k_main(const float* __restrict__ pts,
    const float* __restrict__ wsf,
    const u16b* __restrict__ wb,            // Wb split weights (global, L2-resident)
    u64* __restrict__ pmax, u32* __restrict__ gmax,
    int pmask, int gmask)
{
  __shared__ __align__(16) float sA[4096];     // 16 KB
  __shared__ __align__(16) float sB[12288];    // 48 KB
  const int t = threadIdx.x;
  const int b = blockIdx.x >> 8;
  const int tile = blockIdx.x & 255;
  const int n0 = tile * 64;
  const int ptg = t & 15, pt4 = ptg << 2;
  const int chg = t >> 4;
  const int o4 = chg << 2;
  const int w = t >> 6;            // wave id 0..3
  const int L = t & 63;
  const int qb = (L >> 4) << 2;    // my D-row quad base

  u64* gmS = (u64*)(sB + 448);     // row 7 of A0 region (A0 uses rows 0-6)
  if (t < 4) gmS[t] = 0ull;
  for (int e = t; e < 7*64; e += 256)
    sB[e] = pts[(b*7 + (e >> 6))*NP + n0 + (e & 63)];
  __syncthreads();

  // per-point group id (argmax ch 3..6, first occurrence) -> 64-bit masks
  if (t < 64){
    float v = sB[3*64 + t]; int gi = 0;
    float u1 = sB[4*64 + t]; if (u1 > v){ v = u1; gi = 1; }
    float u2 = sB[5*64 + t]; if (u2 > v){ v = u2; gi = 2; }
    float u3 = sB[6*64 + t]; if (u3 > v){ v = u3; gi = 3; }
    atomicOr(&gmS[gi], 1ull << t);
  }
  __syncthreads();

  // ggpack: 2-bit group id for each of my 16 D-slots (i = m*4+r -> pt = m*16+qb+r)
  u32 g1lo = (u32)gmS[1], g1hi = (u32)(gmS[1] >> 32);
  u32 g2lo = (u32)gmS[2], g2hi = (u32)(gmS[2] >> 32);
  u32 g3lo = (u32)gmS[3], g3hi = (u32)(gmS[3] >> 32);
  u32 ggpack = 0;
  #pragma unroll
  for (int i = 0; i < 16; ++i){
    int m = i >> 2, r = i & 3;
    int sh = ((m & 1) << 4) + qb + r;          // pt&31
    u32 b1 = ((m < 2 ? g1lo : g1hi) >> sh) & 1u;
    u32 b2 = ((m < 2 ? g2lo : g2hi) >> sh) & 1u;
    u32 b3 = ((m < 2 ? g3lo : g3hi) >> sh) & 1u;
    u32 g = b1 + (b2 << 1) + (b3 << 1) + b3;   // 0..3, one-hot source
    ggpack |= g << (2*i);
  }

  f4 acc4[4];
  gemm4<7,64>(sB, wsf + W0T, pt4, o4, acc4);   epi4(acc4, wsf + B0F, o4, sA, pt4);  __syncthreads();
  gemm4<64,64>(sA, wsf + W1T, pt4, o4, acc4);  epi4(acc4, wsf + B1F, o4, sB, pt4);  __syncthreads();
  gemm4<64,64>(sB, wsf + W2T, pt4, o4, acc4);  epi4(acc4, wsf + B2F, o4, sA, pt4);  __syncthreads();

  // L3: compute A4 in-register, split3, write A-frags straight into sB (A2 dead)
  u16b* As = (u16b*)sB;   // [s][m][kc][lane][j] : 3*4*4*64*8 bf16 = 48 KB
  #pragma unroll
  for (int h = 0; h < 2; ++h){
    int kbase = o4 + 64*h;
    gemm4<64,128>(sA, wsf + W3T, pt4, kbase, acc4);
    int kc = kbase >> 5, q = (kbase >> 3) & 3, j0 = kbase & 7;
    #pragma unroll
    for (int jj = 0; jj < 4; ++jj){
      int pt = pt4 + jj;
      int m = pt >> 4, Lf = (pt & 15) | (q << 4);
      u16b hh[4], mm[4], ll[4];
      #pragma unroll
      for (int oi = 0; oi < 4; ++oi){
        float v = fmaxf(((const float*)&acc4[oi])[jj] + wsf[B3F + kbase + oi], 0.f);
        split3(v, hh[oi], mm[oi], ll[oi]);
      }
      u32 base = (u32)(((m*4 + kc)*512) + Lf*8 + j0);
      #pragma unroll
      for (int s = 0; s < 3; ++s){
        const u16b* src = (s == 0) ? hh : (s == 1) ? mm : ll;
        uint2 pk;
        pk.x = (u32)src[0] | ((u32)src[1] << 16);
        pk.y = (u32)src[2] | ((u32)src[3] << 16);
        *(uint2*)(As + (u32)s*8192u + base) = pk;
      }
    }
  }
  __syncthreads();

  // stage bias into sA (sA dead), cache all 48 A-frags in VGPRs
  for (int i = t; i < 1024; i += 256) sA[i] = wsf[B4F + i];
  short8 afr[3][4][4];
  #pragma unroll
  for (int s = 0; s < 3; ++s)
    #pragma unroll
    for (int m = 0; m < 4; ++m)
      #pragma unroll
      for (int kc = 0; kc < 4; ++kc)
        afr[s][m][kc] = *(const short8*)(As + ((s*4 + m)*4 + kc)*512 + L*8);
  __syncthreads();

  u64* pslot = pmax + (size_t)(tile & pmask)*(16*1024) + b*1024;
  u32* gslot = gmax + (size_t)(tile & gmask)*4096;
  const char* wbc = (const char*)wb;
  const u32 bvo = (u32)L * 16u;

  // ---- L4: 16 N-tiles per wave; 6-term split-3 MFMA; reduce from accumulators ----
  for (int nti = 0; nti < 16; ++nti){
    const int nt = (w << 4) + nti;
    const u32 bofs = (u32)nt * 1024u + bvo;
    v4f D[4];
    #pragma unroll
    for (int m = 0; m < 4; ++m) D[m] = (v4f)(0.f);
    #pragma unroll
    for (int kc = 0; kc < 4; ++kc){
      short8 bh = *(const short8*)(wbc +           kc*65536u + bofs);
      short8 bm = *(const short8*)(wbc + 262144u + kc*65536u + bofs);
      short8 bl = *(const short8*)(wbc + 524288u + kc*65536u + bofs);
      #pragma unroll
      for (int m = 0; m < 4; ++m){
        D[m] = __builtin_amdgcn_mfma_f32_16x16x32_bf16(afr[0][m][kc], bh, D[m], 0, 0, 0);
        D[m] = __builtin_amdgcn_mfma_f32_16x16x32_bf16(afr[0][m][kc], bm, D[m], 0, 0, 0);
        D[m] = __builtin_amdgcn_mfma_f32_16x16x32_bf16(afr[1][m][kc], bh, D[m], 0, 0, 0);
        D[m] = __builtin_amdgcn_mfma_f32_16x16x32_bf16(afr[0][m][kc], bl, D[m], 0, 0, 0);
        D[m] = __builtin_amdgcn_mfma_f32_16x16x32_bf16(afr[1][m][kc], bm, D[m], 0, 0, 0);
        D[m] = __builtin_amdgcn_mfma_f32_16x16x32_bf16(afr[2][m][kc], bh, D[m], 0, 0, 0);
      }
    }
    // epilogue: bias+relu, per-lane argmax over 16 slots, group-masked maxes
    float bias = sA[(nt << 4) + (L & 15)];
    float mx = 0.f; int mi = 0;
    float gm0 = 0.f, gm1 = 0.f, gm2 = 0.f, gm3 = 0.f;
    #pragma unroll
    for (int m = 0; m < 4; ++m){
      #pragma unroll
      for (int r = 0; r < 4; ++r){
        int i = m*4 + r;
        float v = fmaxf(D[m][r] + bias, 0.f);
        int pidx = n0 + m*16 + qb + r;
        if (i == 0){ mx = v; mi = pidx; }
        else if (v > mx){ mx = v; mi = pidx; }
        u32 g = (ggpack >> (2*i)) & 3u;
        gm0 = fmaxf(gm0, (g == 0u) ? v : 0.f);
        gm1 = fmaxf(gm1, (g == 1u) ? v : 0.f);
        gm2 = fmaxf(gm2, (g == 2u) ? v : 0.f);
        gm3 = fmaxf(gm3, (g == 3u) ? v : 0.f);
      }
    }
    #pragma unroll
    for (int s = 16; s <= 32; s <<= 1){
      float m2 = __shfl_xor(mx, s);
      int  i2  = __shfl_xor(mi, s);
      if (m2 > mx || (m2 == mx && i2 < mi)){ mx = m2; mi = i2; }
      gm0 = fmaxf(gm0, __shfl_xor(gm0, s));
      gm1 = fmaxf(gm1, __shfl_xor(gm1, s));
      gm2 = fmaxf(gm2, __shfl_xor(gm2, s));
      gm3 = fmaxf(gm3, __shfl_xor(gm3, s));
    }
    if (L < 16){
      int ch = (nt << 4) + L;
      u64 pk = ((u64)__float_as_uint(mx) << 32) | (u64)(0xFFFFFFFFu - (u32)mi);
      atomicMax(pslot + ch, pk);
      if (gm0 > 0.f) atomicMax(gslot + ch,        __float_as_uint(gm0));
      if (gm1 > 0.f) atomicMax(gslot + 1024 + ch, __float_as_uint(gm1));
      if (gm2 > 0.f) atomicMax(gslot + 2048 + ch, __float_as_uint(gm2));
      if (gm3 > 0.f) atomicMax(gslot + 3072 + ch, __float_as_uint(gm3));
    }
  }
}

// ---------------- fold slots; emit max_indices (fp32) + gf + gcf ----------------
__global__ __launch_bounds__(256) void k_reduce(float* __restrict__ wsf, float* __restrict__ out,
                                                u32 pmax_off, u32 gmax_off, int P, int G)
{
  int e = blockIdx.x * 256 + threadIdx.x;          // grid 80 -> 20480
  u64* pmax = (u64*)((char*)wsf + pmax_off);
  u32* gmax = (u32*)((char*)wsf + gmax_off);
  if (e < 16384){
    u64 m = 0ull;
    for (int s = 0; s < P; ++s){ u64 v = pmax[s*16384 + e]; if (v > m) m = v; }
    float val = __uint_as_float((u32)(m >> 32));
    u32 idx = 0xFFFFFFFFu - (u32)(m & 0xFFFFFFFFull);
    wsf[GFO + e] = val;
    out[4096 + e] = (float)idx;                    // max_indices, fp32
  } else if (e < 20480){
    int e2 = e - 16384;
    u32 mg = 0u;
    for (int s = 0; s < G; ++s){ u32 v = gmax[s*4096 + e2]; if (v > mg) mg = v; }
    wsf[GCFO + e2] = __uint_as_float(mg);
  }
}

// ---------------- small MLPs: one wave per dot product ----------------
__global__ __launch_bounds__(256) void k_mlp1(float* __restrict__ wsf,
    const float* __restrict__ wg0, const float* __restrict__ bg0,
    const float* __restrict__ wgr0, const float* __restrict__ bgr0)
{
  int wid = (blockIdx.x * 256 + threadIdx.x) >> 6;   // grid 2176 -> 8704 waves
  int lane = threadIdx.x & 63;
  if (wid < 8192){                                   // of1 = relu(gf @ wg0^T + bg0)
    int b = wid >> 9, o = wid & 511;
    const float* gf = wsf + GFO + b*1024;
    float s = 0.f;
    #pragma unroll
    for (int i = 0; i < 16; ++i){ int k = lane + (i << 6); s = fmaf(gf[k], wg0[o*1024 + k], s); }
    for (int off = 32; off; off >>= 1) s += __shfl_down(s, off);
    if (lane == 0) wsf[OF1O + b*512 + o] = fmaxf(s + bg0[o], 0.f);
  } else if (wid < 8704){                            // gr1 = relu(gcf @ wgr0^T + bgr0)
    int o = wid - 8192;
    const float* gcf = wsf + GCFO;
    float s = 0.f;
    #pragma unroll 8
    for (int i = 0; i < 64; ++i){ int k = lane + (i << 6); s = fmaf(gcf[k], wgr0[o*4096 + k], s); }
    for (int off = 32; off; off >>= 1) s += __shfl_down(s, off);
    if (lane == 0) wsf[GR1O + o] = fmaxf(s + bgr0[o], 0.f);
  }
}

__global__ __launch_bounds__(256) void k_mlp2(const float* __restrict__ wsf,
    const float* __restrict__ wg1, const float* __restrict__ bg1,
    const float* __restrict__ wgr1, const float* __restrict__ bgr1,
    float* __restrict__ out)
{
  int wid = (blockIdx.x * 256 + threadIdx.x) >> 6;   // grid 544 -> 2176 waves
  int lane = threadIdx.x & 63;
  if (wid < 2048){                                   // output_feature -> feature[:,128:256]
    int b = wid >> 7, o = wid & 127;
    const float* of1 = wsf + OF1O + b*512;
    float s = 0.f;
    #pragma unroll
    for (int i = 0; i < 8; ++i){ int k = lane + (i << 6); s = fmaf(of1[k], wg1[o*512 + k], s); }
    for (int off = 32; off; off >>= 1) s += __shfl_down(s, off);
    if (lane == 0) out[b*256 + 128 + o] = fmaxf(s + bg1[o], 0.f);
  } else if (wid < 2176){                            // group_output_feature -> feature[:,0:128]
    int o = wid - 2048;
    const float* gr1 = wsf + GR1O;
    float s = 0.f;
    #pragma unroll
    for (int i = 0; i < 8; ++i){ int k = lane + (i << 6); s = fmaf(gr1[k], wgr1[o*512 + k], s); }
    for (int off = 32; off; off >>= 1) s += __shfl_down(s, off);
    if (lane == 0){
      float r = fmaxf(s + bgr1[o], 0.f);
      for (int bb = 0; bb < 16; ++bb) out[bb*256 + o] = r;   // identical across batch
    }
  }
}

extern "C" void kernel_launch(void* const* d_in, const int* in_sizes, int n_in,
                              void* d_out, int out_size, void* d_ws, size_t ws_size,
                              hipStream_t stream)
{
  const float* pts  = (const float*)d_in[0];
  const float* wl0  = (const float*)d_in[1];  const float* bl0 = (const float*)d_in[2];
  const float* wl1  = (const float*)d_in[3];  const float* bl1 = (const float*)d_in[4];
  const float* wl2  = (const float*)d_in[5];  const float* bl2 = (const float*)d_in[6];
  const float* wl3  = (const float*)d_in[7];  const float* bl3 = (const float*)d_in[8];
  const float* wl4  = (const float*)d_in[9];  const float* bl4 = (const float*)d_in[10];
  const float* wg0  = (const float*)d_in[11]; const float* bg0 = (const float*)d_in[12];
  const float* wg1  = (const float*)d_in[13]; const float* bg1 = (const float*)d_in[14];
  const float* wgr0 = (const float*)d_in[15]; const float* bgr0 = (const float*)d_in[16];
  const float* wgr1 = (const float*)d_in[17]; const float* bgr1 = (const float*)d_in[18];
  float* wsf = (float*)d_ws;
  float* out = (float*)d_out;

  // ws-adaptive: pmax P slots (128 KB), gmax G slots (16 KB), Wb bf16x3 (768 KB)
  int P, G;
  if      (ws_size >= 2400000) { P = 8; G = 16; }   // 2.29 MB
  else if (ws_size >= 1700000) { P = 4; G = 8;  }   // 1.63 MB
  else if (ws_size >= 1360000) { P = 2; G = 4;  }   // 1.30 MB
  else                         { P = 1; G = 2;  }   // 1.14 MB
  u32 pmax_off = FIXED_BYTES;
  u32 gmax_off = pmax_off + (u32)P * 131072u;
  u32 wb_off   = gmax_off + (u32)G * 16384u;

  k_prep<<<dim3(1024), dim3(256), 0, stream>>>(wl0, wl1, wl2, wl3, wl4,
      bl0, bl1, bl2, bl3, bl4, wsf, pmax_off, gmax_off, wb_off, P, G);
  k_main<<<dim3(4096), dim3(256), 0, stream>>>(pts, wsf,
      (const u16b*)((char*)d_ws + wb_off),
      (u64*)((char*)d_ws + pmax_off), (u32*)((char*)d_ws + gmax_off), P-1, G-1);
  k_reduce<<<dim3(80), dim3(256), 0, stream>>>(wsf, out, pmax_off, gmax_off, P, G);
  k_mlp1<<<dim3(2176), dim3(256), 0, stream>>>(wsf, wg0, bg0, wgr0, bgr0);
  k_mlp2<<<dim3(544), dim3(256), 0, stream>>>(wsf, wg1, bg1, wgr1, bgr1, out);
}